// Round 4
// baseline (380.825 us; speedup 1.0000x reference)
//
#include <hip/hip_runtime.h>
#include <hip/hip_bf16.h>
#include <cstdint>
#include <cstddef>

// ---------------------------------------------------------------------------
// SeparableCritic: out = l2norm(MLP(x)) @ l2norm(MLP(y))^T
// N=8192, D=64, H=512, L=128. fp32 I/O, bf16 MFMA internals.
// Round 6 — BISECT: known-good Round-0 baseline + ONE change only.
//   * Final GEMM (K=128) replaced by barrier-free LDS-free gemm_nt_k128:
//     zn (4 MB) is L2-resident, fragments load straight from global; swapped
//     MFMA operands so each lane's f32x4 acc = 4 consecutive cols of one out
//     row -> global_store_dwordx4 epilogue (was 64 scalar stores/lane).
//   * Everything else (encoder GEMMs, separate GEMM3 + l2norm kernels,
//     workspace layout) is byte-identical to the 375 µs baseline.
// Prior two-kernel rewrite died 3x to "container failed twice" with no
// counters; this isolates infra-vs-kernel and bisects the bigger win.
// ---------------------------------------------------------------------------

typedef unsigned short u16;
typedef __attribute__((ext_vector_type(8))) short bf16x8;  // 8 bf16 = 4 VGPRs
typedef __attribute__((ext_vector_type(4))) float f32x4;   // MFMA C/D

__device__ __forceinline__ u16 f_to_bf16_bits(float f) {
    union { float f; uint32_t u; } v; v.f = f;
    uint32_t lsb = (v.u >> 16) & 1u;
    return (u16)((v.u + 0x7fffu + lsb) >> 16);   // round-to-nearest-even
}

// fp32 -> bf16 elementwise cast.
__global__ __launch_bounds__(256) void cast_f32_bf16_kernel(
    const float* __restrict__ in, u16* __restrict__ out, int n)
{
    int i = blockIdx.x * 256 + threadIdx.x;
    if (i < n) out[i] = f_to_bf16_bits(in[i]);
}

// in[R][C] fp32 -> out[C][R] bf16 (weight transpose+cast; tiny, L2-served).
__global__ __launch_bounds__(256) void transpose_cast_kernel(
    const float* __restrict__ in, u16* __restrict__ out, int R, int C)
{
    int idx = blockIdx.x * 256 + threadIdx.x;
    if (idx < R * C) {
        int r = idx / C, c = idx - r * C;
        out[c * R + r] = f_to_bf16_bits(in[r * C + c]);
    }
}

// C[M,N] = act(A[M,K] @ BT[N,K]^T + bias). A,BT row-major bf16.
// Block: 256 thr = 4 waves (2x2), 128x128 tile, each wave 64x64 (4x4 MFMA).
// m97-style global_load_lds staging into fragment-ordered LDS.
template<bool RELU, bool BIAS, bool OUT_F32>
__global__ __launch_bounds__(256) void gemm_lds_kernel(
    const u16* __restrict__ A, const u16* __restrict__ BT,
    const float* __restrict__ bias,
    u16* __restrict__ Cb, float* __restrict__ Cf,
    int M, int N, int K)
{
    __shared__ u16 lds[16 * 512];   // 16 KB
    const int lane = threadIdx.x & 63;
    const int wave = threadIdx.x >> 6;
    const int wm = wave >> 1, wn = wave & 1;
    const int m_base = blockIdx.y * 128;
    const int n_base = blockIdx.x * 128;
    const int mi   = lane & 15;   // frag row / C col within 16-tile
    const int quad = lane >> 4;   // frag k-subrange; C row group

    f32x4 acc[4][4];
    #pragma unroll
    for (int i = 0; i < 4; ++i)
        #pragma unroll
        for (int j = 0; j < 4; ++j)
            acc[i][j] = f32x4{0.f, 0.f, 0.f, 0.f};

    const u16* src[4];
    #pragma unroll
    for (int s = 0; s < 4; ++s) {
        const int t = wave * 4 + s;
        if (t < 8)
            src[s] = A + (size_t)(m_base + t * 16 + mi) * K + quad * 8;
        else
            src[s] = BT + (size_t)(n_base + (t - 8) * 16 + mi) * K + quad * 8;
    }
    u16* dst_base = &lds[wave * 4 * 512];   // wave-uniform

    for (int k0 = 0; k0 < K; k0 += 32) {
        #pragma unroll
        for (int s = 0; s < 4; ++s) {
            __builtin_amdgcn_global_load_lds(
                (const __attribute__((address_space(1))) void*)(src[s] + k0),
                (__attribute__((address_space(3))) void*)(dst_base + s * 512),
                16, 0, 0);
        }
        __syncthreads();

        bf16x8 af[4], bfr[4];
        #pragma unroll
        for (int i = 0; i < 4; ++i)
            af[i] = *reinterpret_cast<const bf16x8*>(&lds[(wm * 4 + i) * 512 + lane * 8]);
        #pragma unroll
        for (int j = 0; j < 4; ++j)
            bfr[j] = *reinterpret_cast<const bf16x8*>(&lds[(8 + wn * 4 + j) * 512 + lane * 8]);

        #pragma unroll
        for (int i = 0; i < 4; ++i)
            #pragma unroll
            for (int j = 0; j < 4; ++j)
                acc[i][j] = __builtin_amdgcn_mfma_f32_16x16x32_bf16(
                    af[i], bfr[j], acc[i][j], 0, 0, 0);

        __syncthreads();
    }

    // Epilogue: C/D layout col = lane&15, row = quad*4 + reg [m89-verified].
    const int wm_base = m_base + wm * 64;
    const int wn_base = n_base + wn * 64;
    #pragma unroll
    for (int j = 0; j < 4; ++j) {
        const int col = wn_base + j * 16 + mi;
        float bv = BIAS ? bias[col] : 0.f;
        #pragma unroll
        for (int i = 0; i < 4; ++i) {
            const int row0 = wm_base + i * 16 + quad * 4;
            #pragma unroll
            for (int r = 0; r < 4; ++r) {
                float v = acc[i][j][r] + bv;
                if (RELU) v = fmaxf(v, 0.f);
                if (OUT_F32) Cf[(size_t)(row0 + r) * N + col] = v;
                else         Cb[(size_t)(row0 + r) * N + col] = f_to_bf16_bits(v);
            }
        }
    }
}

// One wave per row of z[rows][128] fp32: butterfly-reduce sumsq, scale,
// write bf16 packed pair.
__global__ __launch_bounds__(256) void l2norm_kernel(
    const float* __restrict__ z, u16* __restrict__ zn)
{
    const int row  = blockIdx.x * 4 + (threadIdx.x >> 6);
    const int lane = threadIdx.x & 63;
    const float2* zp = reinterpret_cast<const float2*>(z + (size_t)row * 128);
    float2 p = zp[lane];
    float s = p.x * p.x + p.y * p.y;
    #pragma unroll
    for (int off = 32; off > 0; off >>= 1)
        s += __shfl_xor(s, off, 64);
    float inv = 1.0f / fmaxf(sqrtf(s), 1e-12f);
    uint32_t outp = (uint32_t)f_to_bf16_bits(p.x * inv)
                  | ((uint32_t)f_to_bf16_bits(p.y * inv) << 16);
    reinterpret_cast<uint32_t*>(zn + (size_t)row * 128)[lane] = outp;
}

// Final GEMM: out[r][c] = znx[r] . zny[c], K=128, fp32 out. Barrier-free,
// LDS-free: zn is 4 MB -> L2-resident; fragments load straight from global.
// Swapped operands (A-op = zny/col side, B-op = znx/row side) so lane's
// f32x4 acc[ci][rj] = out[rb+rj*16+mi][cb+ci*16+quad*4 .. +3] -> dwordx4
// stores, 64B-contiguous per row per instruction, full lines merged in L2.
__global__ __launch_bounds__(256) void gemm_nt_k128_kernel(
    const u16* __restrict__ ZX, const u16* __restrict__ ZY,
    float* __restrict__ out)
{
    const int lane = threadIdx.x & 63;
    const int wave = threadIdx.x >> 6;
    const int mi   = lane & 15;
    const int quad = lane >> 4;
    const int wr = wave >> 1, wc = wave & 1;
    const int rb = blockIdx.y * 128 + wr * 64;   // out rows (znx)
    const int cb = blockIdx.x * 128 + wc * 64;   // out cols (zny)

    f32x4 acc[4][4];   // [ci][rj]
    #pragma unroll
    for (int ci = 0; ci < 4; ++ci)
        #pragma unroll
        for (int rj = 0; rj < 4; ++rj)
            acc[ci][rj] = f32x4{0.f, 0.f, 0.f, 0.f};

    const u16* xbase = ZX + (size_t)(rb + mi) * 128 + quad * 8;
    const u16* ybase = ZY + (size_t)(cb + mi) * 128 + quad * 8;

    #pragma unroll
    for (int ks = 0; ks < 4; ++ks) {
        bf16x8 yf[4], xf[4];
        #pragma unroll
        for (int t = 0; t < 4; ++t) {
            yf[t] = *reinterpret_cast<const bf16x8*>(ybase + (size_t)t * 16 * 128 + ks * 32);
            xf[t] = *reinterpret_cast<const bf16x8*>(xbase + (size_t)t * 16 * 128 + ks * 32);
        }
        #pragma unroll
        for (int ci = 0; ci < 4; ++ci)
            #pragma unroll
            for (int rj = 0; rj < 4; ++rj)
                acc[ci][rj] = __builtin_amdgcn_mfma_f32_16x16x32_bf16(
                    yf[ci], xf[rj], acc[ci][rj], 0, 0, 0);
    }

    #pragma unroll
    for (int rj = 0; rj < 4; ++rj) {
        float* orow = out + (size_t)(rb + rj * 16 + mi) * 8192 + cb + quad * 4;
        #pragma unroll
        for (int ci = 0; ci < 4; ++ci)
            *reinterpret_cast<f32x4*>(orow + ci * 16) = acc[ci][rj];
    }
}

extern "C" void kernel_launch(void* const* d_in, const int* in_sizes, int n_in,
                              void* d_out, int out_size, void* d_ws, size_t ws_size,
                              hipStream_t stream)
{
    const float* x  = (const float*)d_in[0];   // [8192, 64]
    const float* y  = (const float*)d_in[1];   // [8192, 64]
    const float* W1 = (const float*)d_in[2];   // [64, 512]
    const float* b1 = (const float*)d_in[3];   // [512]
    const float* W2 = (const float*)d_in[4];   // [512, 512]
    const float* b2 = (const float*)d_in[5];   // [512]
    const float* W3 = (const float*)d_in[6];   // [512, 128]
    const float* b3 = (const float*)d_in[7];   // [128]
    float* out = (float*)d_out;                // [8192, 8192] fp32

    // Workspace layout. bf16 regions as u16, z fp32. Total ~47 MB.
    u16* ws  = (u16*)d_ws;
    u16* xy  = ws;                              // [16384][64] bf16
    u16* W1T = xy  + (size_t)16384 * 64;        // [512][64]
    u16* W2T = W1T + 512 * 64;                  // [512][512]
    u16* W3T = W2T + 512 * 512;                 // [128][512]
    u16* h1  = W3T + 128 * 512;                 // [16384][512] bf16
    u16* h2  = h1  + (size_t)16384 * 512;       // [16384][512] bf16
    u16* zn  = h2  + (size_t)16384 * 512;       // [16384][128] bf16
    float* z = (float*)(zn + (size_t)16384 * 128); // [16384][128] fp32

    dim3 blk(256);

    // Cast inputs -> bf16 (x rows 0..8191, y rows 8192..16383).
    cast_f32_bf16_kernel<<<(8192 * 64 + 255) / 256, blk, 0, stream>>>(
        x, xy, 8192 * 64);
    cast_f32_bf16_kernel<<<(8192 * 64 + 255) / 256, blk, 0, stream>>>(
        y, xy + (size_t)8192 * 64, 8192 * 64);

    // Transpose+cast weights to [N][K] bf16.
    transpose_cast_kernel<<<(64 * 512 + 255) / 256, blk, 0, stream>>>(W1, W1T, 64, 512);
    transpose_cast_kernel<<<(512 * 512 + 255) / 256, blk, 0, stream>>>(W2, W2T, 512, 512);
    transpose_cast_kernel<<<(512 * 128 + 255) / 256, blk, 0, stream>>>(W3, W3T, 512, 128);

    // Encoder (shared weights for x and y), batched M=16384.
    gemm_lds_kernel<true, true, false><<<dim3(4, 128), blk, 0, stream>>>(
        xy, W1T, b1, h1, nullptr, 16384, 512, 64);
    gemm_lds_kernel<true, true, false><<<dim3(4, 128), blk, 0, stream>>>(
        h1, W2T, b2, h2, nullptr, 16384, 512, 512);
    gemm_lds_kernel<false, true, true><<<dim3(1, 128), blk, 0, stream>>>(
        h2, W3T, b3, nullptr, z, 16384, 128, 512);

    // L2 normalize fp32 -> bf16 (zx rows 0..8191, zy rows 8192..16383).
    l2norm_kernel<<<16384 / 4, blk, 0, stream>>>(z, zn);

    // out = zx @ zy^T (TEMP=1.0). Barrier-free, write-BW-bound.
    gemm_nt_k128_kernel<<<dim3(64, 64), blk, 0, stream>>>(
        zn, zn + (size_t)8192 * 128, out);
}